// Round 4
// baseline (263.593 us; speedup 1.0000x reference)
//
#include <hip/hip_runtime.h>
#include <stdint.h>

#define BB 1024
#define NN 400
#define EE 128
#define DD 128
#define NSLOT 64
#define GTS 424              // G^T row stride in shorts (400 + pad to 424: 848B rows, 16B aligned, bank-friendly)
#define NKP 212              // k-pairs per G^T row

typedef float f32x4 __attribute__((ext_vector_type(4)));
typedef short bf16x8 __attribute__((ext_vector_type(8)));
typedef short bf16x4 __attribute__((ext_vector_type(4)));

__device__ __forceinline__ short f2bf(float f) {
    uint32_t u = __builtin_bit_cast(uint32_t, f);
    u += 0x7fffu + ((u >> 16) & 1u);
    return (short)(u >> 16);
}

__device__ __forceinline__ float bf2f(short s) {
    return __builtin_bit_cast(float, (uint32_t)((uint16_t)s) << 16);
}

__device__ __forceinline__ bf16x8 cvt8(const f32x4 a, const f32x4 b) {
    bf16x8 r;
    r[0] = f2bf(a[0]); r[1] = f2bf(a[1]); r[2] = f2bf(a[2]); r[3] = f2bf(a[3]);
    r[4] = f2bf(b[0]); r[5] = f2bf(b[1]); r[6] = f2bf(b[2]); r[7] = f2bf(b[3]);
    return r;
}

// K1: one block per b (1024 threads, 16 waves).
//   Phase 0: stage G^T[b] (bf16, [128 d][424 k]) into LDS once.
//   Phase 1 (NO barriers, NO LDS writes): wave w computes P rows w*16..w*16+15:
//     A-fragments loaded directly from global (ss for w<8, es for w>=8),
//     G-fragments via ds_read_b128 from read-only G^T.
//   Phase 2: P' -> Ps (swizzled bf16) + W1 -> LDS bf16; h = X @ W1^T + b1;
//     write h (bf16), BN1 stats via LDS reduce + slot atomics.
__global__ __launch_bounds__(1024, 1)
void k1_gemm(const float* __restrict__ gout, const float* __restrict__ ss,
             const float* __restrict__ es, const float* __restrict__ W1,
             const float* __restrict__ b1, unsigned short* __restrict__ h,
             float* __restrict__ stats1)
{
    __shared__ short lds[66560];           // 130 KB
    short* GT  = lds;                      // [128][424] bf16 (108.5 KB), phase 0/1
    short* Ps  = lds;                      // [256][128] bf16 (64 KB), phase 2 (aliases GT)
    short* W1s = lds + 32768;              // [128][264] bf16 (66 KB), phase 2

    const int b   = blockIdx.x;
    const int t   = threadIdx.x;
    const int w   = t >> 6;                // wave 0..15
    const int l   = t & 63;
    const int l15 = l & 15;
    const int l4  = l >> 4;                // 0..3

    // ---- phase 0: stage G^T (k-pairs packed as b32; lanes -> consecutive d) ----
    {
        const int d   = t & 127;
        const int kpb = t >> 7;            // 0..7
        const float* gb = gout + (size_t)b * NN * DD + d;
        for (int kp = kpb; kp < NKP; kp += 8) {
            int k = 2 * kp;
            float v0 = 0.f, v1 = 0.f;
            if (k < NN) { v0 = gb[(size_t)k * DD]; v1 = gb[(size_t)(k + 1) * DD]; }
            uint32_t pk = (uint32_t)(uint16_t)f2bf(v0) |
                          ((uint32_t)(uint16_t)f2bf(v1) << 16);
            *(uint32_t*)&GT[d * GTS + 2 * kp] = pk;
        }
    }
    __syncthreads();

    // ---- phase 1: P(16 x 128 per wave) = A_rows @ G, barrier-free ----
    const int arow = (w & 7) * 16 + l15;
    const float* abase = ((w < 8) ? ss : es) + ((size_t)b * EE + arow) * NN;

    f32x4 acc[8];
#pragma unroll
    for (int cf = 0; cf < 8; ++cf) acc[cf] = f32x4{0.f, 0.f, 0.f, 0.f};

    auto ld_a = [&](int k0) -> bf16x8 {
        int kk = k0 + l4 * 8;
        f32x4 x0{0.f, 0.f, 0.f, 0.f}, x1{0.f, 0.f, 0.f, 0.f};
        if (kk < NN) { x0 = *(const f32x4*)(abase + kk); x1 = *(const f32x4*)(abase + kk + 4); }
        return cvt8(x0, x1);
    };

    bf16x8 a_cur = ld_a(0);
    const int NK = 13;                     // ceil(400/32); k 400..415 are zeros in GT and predicated in A
    for (int s = 0; s < NK; ++s) {
        bf16x8 a_nxt = a_cur;
        if (s + 1 < NK) a_nxt = ld_a((s + 1) * 32);
        const int k0 = s * 32;
#pragma unroll
        for (int cf = 0; cf < 8; ++cf) {
            bf16x8 gf = *(const bf16x8*)&GT[(cf * 16 + l15) * GTS + k0 + l4 * 8];
            acc[cf] = __builtin_amdgcn_mfma_f32_16x16x32_bf16(a_cur, gf, acc[cf], 0, 0, 0);
        }
        a_cur = a_nxt;
    }
    __syncthreads();                       // GT dead; Ps/W1s regions become live

    // ---- phase 2a: write P' swizzled; stage W1 -> bf16 LDS ----
#pragma unroll
    for (int cf = 0; cf < 8; ++cf)
#pragma unroll
        for (int r = 0; r < 4; ++r) {
            int row = w * 16 + l4 * 4 + r;         // 0..255 (S: 0..127, T: 128..255)
            int col = cf * 16 + l15;
            Ps[row * 128 + (((col >> 3) ^ (row & 7)) << 3) + (col & 7)] = f2bf(acc[cf][r]);
        }
    {
        const int j  = t >> 3;                     // 0..127
        const int kc = t & 7;                      // 32-float chunk
        const float* wp = W1 + (size_t)j * 256 + kc * 32;
        short* dst = &W1s[j * 264 + kc * 32];
#pragma unroll
        for (int i = 0; i < 4; ++i) {
            f32x4 x0 = *(const f32x4*)(wp + i * 8);
            f32x4 x1 = *(const f32x4*)(wp + i * 8 + 4);
            *(bf16x8*)(dst + i * 8) = cvt8(x0, x1);
        }
    }
    __syncthreads();

    // ---- phase 2b: h(16 e-rows x 64 j per wave) = X @ W1^T ----
    const int mt = w >> 1;                 // m-tile: e-rows mt*16..+15
    const int jh = w & 1;                  // j-half
    f32x4 acc2[4];
#pragma unroll
    for (int cf = 0; cf < 4; ++cf) acc2[cf] = f32x4{0.f, 0.f, 0.f, 0.f};

#pragma unroll
    for (int kf = 0; kf < 8; ++kf) {
        int roff = (kf >= 4) ? 128 : 0;    // k<128: P_S rows; k>=128: P_T rows
        int kcol = (kf & 3) * 32 + l4 * 8;
        int row  = roff + mt * 16 + l15;
        int cb   = kcol >> 3;
        bf16x8 xf = *(const bf16x8*)&Ps[row * 128 + ((cb ^ (row & 7)) << 3)];
#pragma unroll
        for (int cf = 0; cf < 4; ++cf) {
            int j = jh * 64 + cf * 16 + l15;
            bf16x8 wf = *(const bf16x8*)&W1s[j * 264 + kf * 32 + l4 * 8];
            acc2[cf] = __builtin_amdgcn_mfma_f32_16x16x32_bf16(xf, wf, acc2[cf], 0, 0, 0);
        }
    }
    __syncthreads();                       // Ps/W1s dead; red region live

    // ---- phase 2c: bias, store h (bf16), BN1 stats ----
    float* red = (float*)lds;              // [256] sums + [256] sumsq
    float s_r[4] = {0.f, 0.f, 0.f, 0.f};
    float q_r[4] = {0.f, 0.f, 0.f, 0.f};
#pragma unroll
    for (int cf = 0; cf < 4; ++cf) {
        float bv = b1[jh * 64 + cf * 16 + l15];
        f32x4 v = acc2[cf] + bv;
#pragma unroll
        for (int r = 0; r < 4; ++r) {
            int e = mt * 16 + l4 * 4 + r;
            h[((size_t)b * EE + e) * DD + jh * 64 + cf * 16 + l15] = (unsigned short)f2bf(v[r]);
            s_r[r] += v[r];
            q_r[r] += v[r] * v[r];
        }
    }
#pragma unroll
    for (int r = 0; r < 4; ++r) {
        float s = s_r[r], q = q_r[r];
        s += __shfl_xor(s, 1); s += __shfl_xor(s, 2); s += __shfl_xor(s, 4); s += __shfl_xor(s, 8);
        q += __shfl_xor(q, 1); q += __shfl_xor(q, 2); q += __shfl_xor(q, 4); q += __shfl_xor(q, 8);
        if (l15 == 0) {
            int e = mt * 16 + l4 * 4 + r;
            red[((e << 1) | jh)]       = s;
            red[256 + ((e << 1) | jh)] = q;
        }
    }
    __syncthreads();
    if (t < 128) {
        float s = red[2 * t] + red[2 * t + 1];
        float q = red[256 + 2 * t] + red[256 + 2 * t + 1];
        int slot = b & (NSLOT - 1);
        atomicAdd(&stats1[slot * 256 + t], s);
        atomicAdd(&stats1[slot * 256 + 128 + t], q);
    }
}

// K3: per b: finalize BN1 (reduce slots), normalize+relu h(bf16) -> bf16 LDS,
// h2 = X @ W2^T + b2 -> d_out (f32 scratch), accumulate BN2 stats.
__global__ __launch_bounds__(256, 4)
void k3_gemm(const unsigned short* __restrict__ h, const float* __restrict__ W2,
             const float* __restrict__ b2, const float* __restrict__ g1,
             const float* __restrict__ bt1, float* __restrict__ out,
             const float* __restrict__ stats1, float* __restrict__ stats2)
{
    __shared__ short Xs[128 * 128];
    __shared__ float sc[128];
    __shared__ float sh[128];
    const int b   = blockIdx.x;
    const int t   = threadIdx.x;
    const int w   = t >> 6;
    const int l15 = t & 15;
    const int l4  = (t >> 4) & 3;

    if (t < 128) {
        float sm = 0.f, sq = 0.f;
#pragma unroll 8
        for (int sl = 0; sl < NSLOT; ++sl) {
            sm += stats1[sl * 256 + t];
            sq += stats1[sl * 256 + 128 + t];
        }
        const float inv_n = 1.0f / (1024.0f * 128.0f);
        float m    = sm * inv_n;
        float var  = sq * inv_n - m * m;
        float rstd = rsqrtf(var + 1e-5f);
        float s    = rstd * g1[t];
        sc[t] = s;
        sh[t] = bt1[t] - m * s;
    }
    __syncthreads();

    {
        const int c8 = t & 15;
        const int eb = t >> 4;
#pragma unroll
        for (int p = 0; p < 8; ++p) {
            int e = eb + 16 * p;
            bf16x8 v8 = *(const bf16x8*)&h[((size_t)b * EE + e) * DD + c8 * 8];
            float s = sc[e], s0 = sh[e];
            bf16x8 o;
#pragma unroll
            for (int i = 0; i < 8; ++i)
                o[i] = f2bf(fmaxf(fmaf(bf2f(v8[i]), s, s0), 0.0f));
            *(bf16x8*)&Xs[e * 128 + ((c8 ^ (e & 7)) << 3)] = o;
        }
    }
    __syncthreads();

    f32x4 acc[8][2];
#pragma unroll
    for (int i = 0; i < 8; ++i) {
        acc[i][0] = f32x4{0.f, 0.f, 0.f, 0.f};
        acc[i][1] = f32x4{0.f, 0.f, 0.f, 0.f};
    }
#pragma unroll
    for (int kf = 0; kf < 4; ++kf) {
        const int k0 = kf * 32;
        const int cb = (k0 >> 3) + l4;
        bf16x8 af[8];
#pragma unroll
        for (int rf = 0; rf < 8; ++rf) {
            int row = rf * 16 + l15;
            af[rf] = *(const bf16x8*)&Xs[row * 128 + ((cb ^ (row & 7)) * 8)];
        }
#pragma unroll
        for (int cf = 0; cf < 2; ++cf) {
            int j = w * 32 + cf * 16 + l15;
            const float* wp = W2 + (size_t)j * 128 + k0 + l4 * 8;
            bf16x8 bfr = cvt8(*(const f32x4*)wp, *(const f32x4*)(wp + 4));
#pragma unroll
            for (int rf = 0; rf < 8; ++rf)
                acc[rf][cf] = __builtin_amdgcn_mfma_f32_16x16x32_bf16(af[rf], bfr, acc[rf][cf], 0, 0, 0);
        }
    }

    __syncthreads();
    float* red = (float*)Xs;
    const float bj0 = b2[w * 32 + l15];
    const float bj1 = b2[w * 32 + 16 + l15];
    const int j0 = w * 32 + l15;
#pragma unroll
    for (int rf = 0; rf < 8; ++rf) {
        f32x4 v0 = acc[rf][0] + bj0;
        f32x4 v1 = acc[rf][1] + bj1;
        int elb = rf * 16 + l4 * 4;
#pragma unroll
        for (int r = 0; r < 4; ++r) {
            float* op = out + (size_t)(b * EE + elb + r) * DD;
            op[j0]      = v0[r];
            op[j0 + 16] = v1[r];
            float s = v0[r] + v1[r];
            float q = v0[r] * v0[r] + v1[r] * v1[r];
            s += __shfl_xor(s, 1); s += __shfl_xor(s, 2); s += __shfl_xor(s, 4); s += __shfl_xor(s, 8);
            q += __shfl_xor(q, 1); q += __shfl_xor(q, 2); q += __shfl_xor(q, 4); q += __shfl_xor(q, 8);
            if (l15 == 0) {
                red[(elb + r) * 4 + w]       = s;
                red[512 + (elb + r) * 4 + w] = q;
            }
        }
    }
    __syncthreads();
    if (t < 128) {
        float s = red[t * 4] + red[t * 4 + 1] + red[t * 4 + 2] + red[t * 4 + 3];
        float q = red[512 + t * 4] + red[512 + t * 4 + 1] + red[512 + t * 4 + 2] + red[512 + t * 4 + 3];
        int slot = b & (NSLOT - 1);
        atomicAdd(&stats2[slot * 256 + t], s);
        atomicAdd(&stats2[slot * 256 + 128 + t], q);
    }
}

// K5: finalize BN2, out = relu(eout + h2*scale + shift), in-place on d_out.
__global__ __launch_bounds__(256)
void k5_final(const float* __restrict__ eout, const float* __restrict__ g2,
              const float* __restrict__ bt2, float* __restrict__ io,
              const float* __restrict__ stats2)
{
    __shared__ float sc[128];
    __shared__ float sh[128];
    const int t = threadIdx.x;
    if (t < 128) {
        float sm = 0.f, sq = 0.f;
#pragma unroll 8
        for (int sl = 0; sl < NSLOT; ++sl) {
            sm += stats2[sl * 256 + t];
            sq += stats2[sl * 256 + 128 + t];
        }
        const float inv_n = 1.0f / (1024.0f * 128.0f);
        float m    = sm * inv_n;
        float var  = sq * inv_n - m * m;
        float rstd = rsqrtf(var + 1e-5f);
        float s    = rstd * g2[t];
        sc[t] = s;
        sh[t] = bt2[t] - m * s;
    }
    __syncthreads();

    const int total4 = BB * EE * DD / 4;
    for (int i4 = blockIdx.x * blockDim.x + t; i4 < total4; i4 += gridDim.x * blockDim.x) {
        int e = (i4 >> 5) & 127;
        f32x4 v = *(f32x4*)(io + (size_t)i4 * 4);
        f32x4 u = *(const f32x4*)(eout + (size_t)i4 * 4);
        float s = sc[e], s0 = sh[e];
        f32x4 o;
#pragma unroll
        for (int i = 0; i < 4; ++i)
            o[i] = fmaxf(u[i] + fmaf(v[i], s, s0), 0.0f);
        *(f32x4*)(io + (size_t)i4 * 4) = o;
    }
}

extern "C" void kernel_launch(void* const* d_in, const int* in_sizes, int n_in,
                              void* d_out, int out_size, void* d_ws, size_t ws_size,
                              hipStream_t stream)
{
    const float* gout  = (const float*)d_in[0];
    const float* eout  = (const float*)d_in[1];
    const float* ss    = (const float*)d_in[2];
    const float* es    = (const float*)d_in[3];
    const float* W1    = (const float*)d_in[4];
    const float* b1    = (const float*)d_in[5];
    const float* W2    = (const float*)d_in[6];
    const float* b2    = (const float*)d_in[7];
    const float* g1    = (const float*)d_in[8];
    const float* bt1   = (const float*)d_in[9];
    const float* g2    = (const float*)d_in[10];
    const float* bt2   = (const float*)d_in[11];

    float* stats1 = (float*)d_ws;                       // [64][256]
    float* stats2 = stats1 + NSLOT * 256;               // [64][256]
    unsigned short* h = (unsigned short*)(stats2 + NSLOT * 256);  // [B][E][D] bf16
    float* out    = (float*)d_out;

    hipMemsetAsync((void*)stats1, 0, 2 * NSLOT * 256 * sizeof(float), stream);
    k1_gemm<<<dim3(BB), dim3(1024), 0, stream>>>(gout, ss, es, W1, b1, h, stats1);
    k3_gemm<<<dim3(BB), dim3(256), 0, stream>>>(h, W2, b2, g1, bt1, out, stats1, stats2);
    k5_final<<<dim3(2048), dim3(256), 0, stream>>>(eout, g2, bt2, out, stats2);
}

// Round 5
// 246.912 us; speedup vs baseline: 1.0676x; 1.0676x over previous
//
#include <hip/hip_runtime.h>
#include <stdint.h>

#define BB 1024
#define NN 400
#define EE 128
#define DD 128
#define NSLOT 64
#define GTS 424              // G^T row stride in shorts

typedef float f32x4 __attribute__((ext_vector_type(4)));
typedef short bf16x8 __attribute__((ext_vector_type(8)));
typedef short bf16x4 __attribute__((ext_vector_type(4)));

__device__ __forceinline__ short f2bf(float f) {
    uint32_t u = __builtin_bit_cast(uint32_t, f);
    u += 0x7fffu + ((u >> 16) & 1u);
    return (short)(u >> 16);
}

__device__ __forceinline__ float bf2f(short s) {
    return __builtin_bit_cast(float, (uint32_t)((uint16_t)s) << 16);
}

__device__ __forceinline__ bf16x8 cvt8(const f32x4 a, const f32x4 b) {
    bf16x8 r;
    r[0] = f2bf(a[0]); r[1] = f2bf(a[1]); r[2] = f2bf(a[2]); r[3] = f2bf(a[3]);
    r[4] = f2bf(b[0]); r[5] = f2bf(b[1]); r[6] = f2bf(b[2]); r[7] = f2bf(b[3]);
    return r;
}

// K1: one block per b (1024 threads, 16 waves).
//   Pre-issue A loads for K-steps 0,1 (raw f32, latency hidden under phase 0).
//   Phase 0: stage G^T[b] (bf16 [128][424]) via quad-pack b64 LDS writes.
//   Phase 1 (barrier-free): 13 K-steps; 2-deep raw-f32 A prefetch ring,
//     cvt deferred 2 iterations; 8 ds_read_b128 + 8 MFMA per step.
//   Phase 2: P' -> Ps swizzled + W1 -> LDS; h = X @ W1^T + b1; h bf16 + BN1 stats.
__global__ __launch_bounds__(1024, 1)
void k1_gemm(const float* __restrict__ gout, const float* __restrict__ ss,
             const float* __restrict__ es, const float* __restrict__ W1,
             const float* __restrict__ b1, unsigned short* __restrict__ h,
             float* __restrict__ stats1)
{
    __shared__ short lds[66560];           // 130 KB
    short* GT  = lds;                      // [128][424] bf16, phase 0/1
    short* Ps  = lds;                      // [256][128] bf16, phase 2 (aliases GT)
    short* W1s = lds + 32768;              // [128][264] bf16, phase 2

    const int b   = blockIdx.x;
    const int t   = threadIdx.x;
    const int w   = t >> 6;                // wave 0..15
    const int l   = t & 63;
    const int l15 = l & 15;
    const int l4  = l >> 4;                // 0..3

    // ---- pre-issue A loads for K-steps 0 and 1 (raw f32; cvt much later) ----
    const int arow = (w & 7) * 16 + l15;
    const float* abase = ((w < 8) ? ss : es) + ((size_t)b * EE + arow) * NN;
    const int kkoff = l4 * 8;

    f32x4 pa0 = *(const f32x4*)(abase + kkoff);
    f32x4 pa1 = *(const f32x4*)(abase + kkoff + 4);
    f32x4 pb0 = *(const f32x4*)(abase + 32 + kkoff);
    f32x4 pb1 = *(const f32x4*)(abase + 32 + kkoff + 4);

    // ---- phase 0: stage G^T (4-k quads per thread, b64 writes) ----
    {
        const int d  = t & 127;
        const int qb = t >> 7;             // 0..7
        const float* gb = gout + (size_t)b * NN * DD + d;
        for (int q = qb; q < 106; q += 8) {
            int k = 4 * q;
            float v0 = 0.f, v1 = 0.f, v2 = 0.f, v3 = 0.f;
            if (k < NN) {                  // k<=396 -> k..k+3 all in range
                v0 = gb[(size_t)k * DD];
                v1 = gb[(size_t)(k + 1) * DD];
                v2 = gb[(size_t)(k + 2) * DD];
                v3 = gb[(size_t)(k + 3) * DD];
            }
            uint32_t lo = (uint32_t)(uint16_t)f2bf(v0) | ((uint32_t)(uint16_t)f2bf(v1) << 16);
            uint32_t hi = (uint32_t)(uint16_t)f2bf(v2) | ((uint32_t)(uint16_t)f2bf(v3) << 16);
            *(uint64_t*)&GT[d * GTS + 4 * q] = ((uint64_t)hi << 32) | lo;
        }
    }
    __syncthreads();

    // ---- phase 1: P(16 x 128 per wave) = A_rows @ G, barrier-free ----
    f32x4 acc[8];
#pragma unroll
    for (int cf = 0; cf < 8; ++cf) acc[cf] = f32x4{0.f, 0.f, 0.f, 0.f};

#pragma unroll
    for (int s = 0; s < 13; ++s) {
        bf16x8 a = cvt8(pa0, pa1);         // loads from 2 iterations ago
        pa0 = pb0; pa1 = pb1;
        const int sn = s + 2;
        if (sn < 12) {
            pb0 = *(const f32x4*)(abase + sn * 32 + kkoff);
            pb1 = *(const f32x4*)(abase + sn * 32 + kkoff + 4);
        } else if (sn == 12) {
            int kk = 384 + kkoff;
            pb0 = f32x4{0.f, 0.f, 0.f, 0.f};
            pb1 = f32x4{0.f, 0.f, 0.f, 0.f};
            if (kk < NN)     pb0 = *(const f32x4*)(abase + kk);
            if (kk + 4 < NN) pb1 = *(const f32x4*)(abase + kk + 4);
        }
        const int k0 = s * 32;
#pragma unroll
        for (int cf = 0; cf < 8; ++cf) {
            bf16x8 gf = *(const bf16x8*)&GT[(cf * 16 + l15) * GTS + k0 + kkoff];
            acc[cf] = __builtin_amdgcn_mfma_f32_16x16x32_bf16(a, gf, acc[cf], 0, 0, 0);
        }
    }
    __syncthreads();                       // GT dead; Ps/W1s live

    // ---- phase 2a: write P' swizzled; stage W1 -> bf16 LDS ----
#pragma unroll
    for (int cf = 0; cf < 8; ++cf)
#pragma unroll
        for (int r = 0; r < 4; ++r) {
            int row = w * 16 + l4 * 4 + r;         // 0..255 (S rows, then T rows)
            int col = cf * 16 + l15;
            Ps[row * 128 + (((col >> 3) ^ (row & 7)) << 3) + (col & 7)] = f2bf(acc[cf][r]);
        }
    {
        const int j  = t >> 3;                     // 0..127
        const int kc = t & 7;
        const float* wp = W1 + (size_t)j * 256 + kc * 32;
        short* dst = &W1s[j * 264 + kc * 32];
#pragma unroll
        for (int i = 0; i < 4; ++i) {
            f32x4 x0 = *(const f32x4*)(wp + i * 8);
            f32x4 x1 = *(const f32x4*)(wp + i * 8 + 4);
            *(bf16x8*)(dst + i * 8) = cvt8(x0, x1);
        }
    }
    __syncthreads();

    // ---- phase 2b: h(16 e-rows x 64 j per wave) = X @ W1^T ----
    const int mt = w >> 1;
    const int jh = w & 1;
    f32x4 acc2[4];
#pragma unroll
    for (int cf = 0; cf < 4; ++cf) acc2[cf] = f32x4{0.f, 0.f, 0.f, 0.f};

#pragma unroll
    for (int kf = 0; kf < 8; ++kf) {
        int roff = (kf >= 4) ? 128 : 0;
        int kcol = (kf & 3) * 32 + l4 * 8;
        int row  = roff + mt * 16 + l15;
        int cb   = kcol >> 3;
        bf16x8 xf = *(const bf16x8*)&Ps[row * 128 + ((cb ^ (row & 7)) << 3)];
#pragma unroll
        for (int cf = 0; cf < 4; ++cf) {
            int j = jh * 64 + cf * 16 + l15;
            bf16x8 wf = *(const bf16x8*)&W1s[j * 264 + kf * 32 + l4 * 8];
            acc2[cf] = __builtin_amdgcn_mfma_f32_16x16x32_bf16(xf, wf, acc2[cf], 0, 0, 0);
        }
    }
    __syncthreads();                       // Ps/W1s dead; red live

    // ---- phase 2c: bias, store h (bf16), BN1 stats ----
    float* red = (float*)lds;
    float s_r[4] = {0.f, 0.f, 0.f, 0.f};
    float q_r[4] = {0.f, 0.f, 0.f, 0.f};
#pragma unroll
    for (int cf = 0; cf < 4; ++cf) {
        float bv = b1[jh * 64 + cf * 16 + l15];
        f32x4 v = acc2[cf] + bv;
#pragma unroll
        for (int r = 0; r < 4; ++r) {
            int e = mt * 16 + l4 * 4 + r;
            h[((size_t)b * EE + e) * DD + jh * 64 + cf * 16 + l15] = (unsigned short)f2bf(v[r]);
            s_r[r] += v[r];
            q_r[r] += v[r] * v[r];
        }
    }
#pragma unroll
    for (int r = 0; r < 4; ++r) {
        float s = s_r[r], q = q_r[r];
        s += __shfl_xor(s, 1); s += __shfl_xor(s, 2); s += __shfl_xor(s, 4); s += __shfl_xor(s, 8);
        q += __shfl_xor(q, 1); q += __shfl_xor(q, 2); q += __shfl_xor(q, 4); q += __shfl_xor(q, 8);
        if (l15 == 0) {
            int e = mt * 16 + l4 * 4 + r;
            red[((e << 1) | jh)]       = s;
            red[256 + ((e << 1) | jh)] = q;
        }
    }
    __syncthreads();
    if (t < 128) {
        float s = red[2 * t] + red[2 * t + 1];
        float q = red[256 + 2 * t] + red[256 + 2 * t + 1];
        int slot = b & (NSLOT - 1);
        atomicAdd(&stats1[slot * 256 + t], s);
        atomicAdd(&stats1[slot * 256 + 128 + t], q);
    }
}

// K3: per b: finalize BN1, normalize+relu h(bf16) -> bf16 LDS,
// h2 = X @ W2^T + b2 -> written IN-PLACE over h (bf16), BN2 stats.
// Safe overlay: all reads of h[b] complete (barrier) before writes to h[b].
__global__ __launch_bounds__(256, 4)
void k3_gemm(unsigned short* h, const float* __restrict__ W2,
             const float* __restrict__ b2, const float* __restrict__ g1,
             const float* __restrict__ bt1,
             const float* __restrict__ stats1, float* __restrict__ stats2)
{
    __shared__ short Xs[128 * 128];
    __shared__ float sc[128];
    __shared__ float sh[128];
    const int b   = blockIdx.x;
    const int t   = threadIdx.x;
    const int w   = t >> 6;
    const int l15 = t & 15;
    const int l4  = (t >> 4) & 3;

    if (t < 128) {
        float sm = 0.f, sq = 0.f;
#pragma unroll 8
        for (int sl = 0; sl < NSLOT; ++sl) {
            sm += stats1[sl * 256 + t];
            sq += stats1[sl * 256 + 128 + t];
        }
        const float inv_n = 1.0f / (1024.0f * 128.0f);
        float m    = sm * inv_n;
        float var  = sq * inv_n - m * m;
        float rstd = rsqrtf(var + 1e-5f);
        float s    = rstd * g1[t];
        sc[t] = s;
        sh[t] = bt1[t] - m * s;
    }
    __syncthreads();

    {
        const int c8 = t & 15;
        const int eb = t >> 4;
#pragma unroll
        for (int p = 0; p < 8; ++p) {
            int e = eb + 16 * p;
            bf16x8 v8 = *(const bf16x8*)&h[((size_t)b * EE + e) * DD + c8 * 8];
            float s = sc[e], s0 = sh[e];
            bf16x8 o;
#pragma unroll
            for (int i = 0; i < 8; ++i)
                o[i] = f2bf(fmaxf(fmaf(bf2f(v8[i]), s, s0), 0.0f));
            *(bf16x8*)&Xs[e * 128 + ((c8 ^ (e & 7)) << 3)] = o;
        }
    }
    __syncthreads();

    f32x4 acc[8][2];
#pragma unroll
    for (int i = 0; i < 8; ++i) {
        acc[i][0] = f32x4{0.f, 0.f, 0.f, 0.f};
        acc[i][1] = f32x4{0.f, 0.f, 0.f, 0.f};
    }
#pragma unroll
    for (int kf = 0; kf < 4; ++kf) {
        const int k0 = kf * 32;
        const int cb = (k0 >> 3) + l4;
        bf16x8 af[8];
#pragma unroll
        for (int rf = 0; rf < 8; ++rf) {
            int row = rf * 16 + l15;
            af[rf] = *(const bf16x8*)&Xs[row * 128 + ((cb ^ (row & 7)) * 8)];
        }
#pragma unroll
        for (int cf = 0; cf < 2; ++cf) {
            int j = w * 32 + cf * 16 + l15;
            const float* wp = W2 + (size_t)j * 128 + k0 + l4 * 8;
            bf16x8 bfr = cvt8(*(const f32x4*)wp, *(const f32x4*)(wp + 4));
#pragma unroll
            for (int rf = 0; rf < 8; ++rf)
                acc[rf][cf] = __builtin_amdgcn_mfma_f32_16x16x32_bf16(af[rf], bfr, acc[rf][cf], 0, 0, 0);
        }
    }

    __syncthreads();
    float* red = (float*)Xs;
    const float bj0 = b2[w * 32 + l15];
    const float bj1 = b2[w * 32 + 16 + l15];
    const int j0 = w * 32 + l15;
#pragma unroll
    for (int rf = 0; rf < 8; ++rf) {
        f32x4 v0 = acc[rf][0] + bj0;
        f32x4 v1 = acc[rf][1] + bj1;
        int elb = rf * 16 + l4 * 4;
#pragma unroll
        for (int r = 0; r < 4; ++r) {
            unsigned short* op = h + (size_t)(b * EE + elb + r) * DD;
            op[j0]      = (unsigned short)f2bf(v0[r]);
            op[j0 + 16] = (unsigned short)f2bf(v1[r]);
            float s = v0[r] + v1[r];
            float q = v0[r] * v0[r] + v1[r] * v1[r];
            s += __shfl_xor(s, 1); s += __shfl_xor(s, 2); s += __shfl_xor(s, 4); s += __shfl_xor(s, 8);
            q += __shfl_xor(q, 1); q += __shfl_xor(q, 2); q += __shfl_xor(q, 4); q += __shfl_xor(q, 8);
            if (l15 == 0) {
                red[(elb + r) * 4 + w]       = s;
                red[512 + (elb + r) * 4 + w] = q;
            }
        }
    }
    __syncthreads();
    if (t < 128) {
        float s = red[t * 4] + red[t * 4 + 1] + red[t * 4 + 2] + red[t * 4 + 3];
        float q = red[512 + t * 4] + red[512 + t * 4 + 1] + red[512 + t * 4 + 2] + red[512 + t * 4 + 3];
        int slot = b & (NSLOT - 1);
        atomicAdd(&stats2[slot * 256 + t], s);
        atomicAdd(&stats2[slot * 256 + 128 + t], q);
    }
}

// K5: finalize BN2, out = relu(eout + h2*scale + shift); h2 is bf16.
__global__ __launch_bounds__(256)
void k5_final(const unsigned short* __restrict__ h2, const float* __restrict__ eout,
              const float* __restrict__ g2, const float* __restrict__ bt2,
              float* __restrict__ out, const float* __restrict__ stats2)
{
    __shared__ float sc[128];
    __shared__ float sh[128];
    const int t = threadIdx.x;
    if (t < 128) {
        float sm = 0.f, sq = 0.f;
#pragma unroll 8
        for (int sl = 0; sl < NSLOT; ++sl) {
            sm += stats2[sl * 256 + t];
            sq += stats2[sl * 256 + 128 + t];
        }
        const float inv_n = 1.0f / (1024.0f * 128.0f);
        float m    = sm * inv_n;
        float var  = sq * inv_n - m * m;
        float rstd = rsqrtf(var + 1e-5f);
        float s    = rstd * g2[t];
        sc[t] = s;
        sh[t] = bt2[t] - m * s;
    }
    __syncthreads();

    const int total8 = BB * EE * DD / 8;
    for (int i8 = blockIdx.x * blockDim.x + t; i8 < total8; i8 += gridDim.x * blockDim.x) {
        int e = (i8 >> 4) & 127;
        bf16x8 v8 = *(const bf16x8*)(h2 + (size_t)i8 * 8);
        f32x4 u0 = *(const f32x4*)(eout + (size_t)i8 * 8);
        f32x4 u1 = *(const f32x4*)(eout + (size_t)i8 * 8 + 4);
        float s = sc[e], s0 = sh[e];
        f32x4 o0, o1;
#pragma unroll
        for (int i = 0; i < 4; ++i) {
            o0[i] = fmaxf(u0[i] + fmaf(bf2f(v8[i]), s, s0), 0.0f);
            o1[i] = fmaxf(u1[i] + fmaf(bf2f(v8[i + 4]), s, s0), 0.0f);
        }
        *(f32x4*)(out + (size_t)i8 * 8)     = o0;
        *(f32x4*)(out + (size_t)i8 * 8 + 4) = o1;
    }
}

extern "C" void kernel_launch(void* const* d_in, const int* in_sizes, int n_in,
                              void* d_out, int out_size, void* d_ws, size_t ws_size,
                              hipStream_t stream)
{
    const float* gout  = (const float*)d_in[0];
    const float* eout  = (const float*)d_in[1];
    const float* ss    = (const float*)d_in[2];
    const float* es    = (const float*)d_in[3];
    const float* W1    = (const float*)d_in[4];
    const float* b1    = (const float*)d_in[5];
    const float* W2    = (const float*)d_in[6];
    const float* b2    = (const float*)d_in[7];
    const float* g1    = (const float*)d_in[8];
    const float* bt1   = (const float*)d_in[9];
    const float* g2    = (const float*)d_in[10];
    const float* bt2   = (const float*)d_in[11];

    float* stats1 = (float*)d_ws;                       // [64][256]
    float* stats2 = stats1 + NSLOT * 256;               // [64][256]
    unsigned short* h = (unsigned short*)(stats2 + NSLOT * 256);  // [B][E][D] bf16 (h, then h2 in-place)
    float* out    = (float*)d_out;

    hipMemsetAsync((void*)stats1, 0, 2 * NSLOT * 256 * sizeof(float), stream);
    k1_gemm<<<dim3(BB), dim3(1024), 0, stream>>>(gout, ss, es, W1, b1, h, stats1);
    k3_gemm<<<dim3(BB), dim3(256), 0, stream>>>(h, W2, b2, g1, bt1, stats1, stats2);
    k5_final<<<dim3(2048), dim3(256), 0, stream>>>(h, eout, g2, bt2, out, stats2);
}